// Round 13
// baseline (307.142 us; speedup 1.0000x reference)
//
#include <hip/hip_runtime.h>

#define NN  8193       // output cols per row; u length
#define FN  16384      // complex FFT length (real conv length 32768)
#define NTHR 1024      // threads per FFT block (16 waves/CU, VGPR cap 128 via launch_bounds)

// LDS swizzle-pad. Bank-pair stride classes (mod 16): 1->1, 4->4, 64->5,
// 256->4, 1024->1. Injective. Max ZIDX(16383) = 17676.
#define ZIDX(i) ((i) + ((i) >> 4) + ((i) >> 6) + ((i) >> 10))
#define ZPAD 17680

// workspace byte offsets (256-aligned)
#define OFF_BANDS 0u        // 3*2049*4 = 24588
#define OFF_AF32  24832u    // 16385*4 = 65540
#define OFF_AHAT  90624u    // 16385*8 = 131080
#define OFF_TW    221952u   // 12288*8 = 98304  (w_N^e, e in [0,12288))
#define OFF_TAU   320256u   // 16385*8 = 131080 (exp(-i pi k/N), k in [0,16384])

__device__ __forceinline__ float2 cmul(float2 a, float2 b) {
  return make_float2(a.x * b.x - a.y * b.y, a.x * b.y + a.y * b.x);
}
__device__ __forceinline__ float2 cadd(float2 a, float2 b) { return make_float2(a.x + b.x, a.y + b.y); }
__device__ __forceinline__ float2 csub(float2 a, float2 b) { return make_float2(a.x - b.x, a.y - b.y); }

// base-4 digit reversal of 7 digits (14 bits)
__device__ __forceinline__ int rev4_14(int k) {
  int r = 0;
  #pragma unroll
  for (int i = 0; i < 7; ++i) { r = (r << 2) | (k & 3); k >>= 2; }
  return r;
}

// Affine swizzled-offset constants: ZIDX(base + k*Q2) = ZIDX(base) + zoffk<Q1>(k).
// Valid by range analysis (j2 < Q2): no carry crosses the shift boundaries.
//   Q1=4096 (Q2=1024): C = 1024+64+16+1 = 1105
//   Q1=256  (Q2=64):   C = 64+4+1      = 69
//   Q1=16   (Q2=4):    4k + (k>>2)     (4(k&3)+j2 <= 15 < 16)
template<int Q1>
__device__ __forceinline__ constexpr int zoffk(int k) {
  return (Q1 == 4096) ? 1105 * k : (Q1 == 256) ? 69 * k : (4 * k + (k >> 2));
}

// ---- fused double radix-4 stage, forward (R11/R12-verified formulas) ----
template<int Q1, int M1>
__device__ __forceinline__ void ds_fwd(float2* Z, const float2* __restrict__ tw,
                                       int tid) {
  constexpr int Q2 = Q1 >> 2;
  constexpr int M2 = M1 << 2;
  const int b1 = tid / Q2;           // compile-time shift
  const int j2 = tid & (Q2 - 1);
  const int z0 = ZIDX(b1 * 4 * Q1 + j2);
  float2 c[4][4];  // [q1][q2]
  #pragma unroll
  for (int q1 = 0; q1 < 4; ++q1)
    #pragma unroll
    for (int q2 = 0; q2 < 4; ++q2)
      c[q1][q2] = Z[z0 + zoffk<Q1>(q1 * 4 + q2)];
  #pragma unroll
  for (int q2 = 0; q2 < 4; ++q2) {
    const int e = (j2 + q2 * Q2) * M1;
    const float2 w1 = tw[e], w2 = tw[2 * e], w3 = tw[3 * e];
    float2 c0 = c[0][q2], c1 = c[1][q2], c2 = c[2][q2], c3 = c[3][q2];
    float2 t0 = cadd(c0, c2), t1 = csub(c0, c2), t2 = cadd(c1, c3);
    float2 t3 = make_float2(c1.y - c3.y, -(c1.x - c3.x));   // -i*(c1-c3)
    c[0][q2] = cadd(t0, t2);
    c[1][q2] = cmul(w1, cadd(t1, t3));
    c[2][q2] = cmul(w2, csub(t0, t2));
    c[3][q2] = cmul(w3, csub(t1, t3));
  }
  const int e2 = j2 * M2;
  const float2 v1 = tw[e2], v2 = tw[2 * e2], v3 = tw[3 * e2];
  #pragma unroll
  for (int p1 = 0; p1 < 4; ++p1) {
    float2 c0 = c[p1][0], c1 = c[p1][1], c2 = c[p1][2], c3 = c[p1][3];
    float2 t0 = cadd(c0, c2), t1 = csub(c0, c2), t2 = cadd(c1, c3);
    float2 t3 = make_float2(c1.y - c3.y, -(c1.x - c3.x));
    c[p1][0] = cadd(t0, t2);
    c[p1][1] = cmul(v1, cadd(t1, t3));
    c[p1][2] = cmul(v2, csub(t0, t2));
    c[p1][3] = cmul(v3, csub(t1, t3));
  }
  #pragma unroll
  for (int p1 = 0; p1 < 4; ++p1)
    #pragma unroll
    for (int p2 = 0; p2 < 4; ++p2)
      Z[z0 + zoffk<Q1>(p1 * 4 + p2)] = c[p1][p2];
}

// ---- fused double stage, exact adjoint ----
template<int Q1, int M1>
__device__ __forceinline__ void ds_inv(float2* Z, const float2* __restrict__ tw,
                                       int tid) {
  constexpr int Q2 = Q1 >> 2;
  constexpr int M2 = M1 << 2;
  const int b1 = tid / Q2;
  const int j2 = tid & (Q2 - 1);
  const int z0 = ZIDX(b1 * 4 * Q1 + j2);
  float2 c[4][4];  // [p1][p2]
  #pragma unroll
  for (int p1 = 0; p1 < 4; ++p1)
    #pragma unroll
    for (int p2 = 0; p2 < 4; ++p2)
      c[p1][p2] = Z[z0 + zoffk<Q1>(p1 * 4 + p2)];
  const int e2 = j2 * M2;
  float2 v1 = tw[e2], v2 = tw[2 * e2], v3 = tw[3 * e2];
  v1.y = -v1.y; v2.y = -v2.y; v3.y = -v3.y;
  #pragma unroll
  for (int p1 = 0; p1 < 4; ++p1) {
    float2 u0 = c[p1][0];
    float2 u1 = cmul(v1, c[p1][1]);
    float2 u2 = cmul(v2, c[p1][2]);
    float2 u3 = cmul(v3, c[p1][3]);
    float2 s0 = cadd(u0, u2), s1 = csub(u0, u2), s2 = cadd(u1, u3);
    float2 s3 = make_float2(-(u1.y - u3.y), u1.x - u3.x);  // +i*(u1-u3)
    c[p1][0] = cadd(s0, s2);
    c[p1][1] = cadd(s1, s3);
    c[p1][2] = csub(s0, s2);
    c[p1][3] = csub(s1, s3);
  }
  #pragma unroll
  for (int q2 = 0; q2 < 4; ++q2) {
    const int e = (j2 + q2 * Q2) * M1;
    float2 w1 = tw[e], w2 = tw[2 * e], w3 = tw[3 * e];
    w1.y = -w1.y; w2.y = -w2.y; w3.y = -w3.y;
    float2 u0 = c[0][q2];
    float2 u1 = cmul(w1, c[1][q2]);
    float2 u2 = cmul(w2, c[2][q2]);
    float2 u3 = cmul(w3, c[3][q2]);
    float2 s0 = cadd(u0, u2), s1 = csub(u0, u2), s2 = cadd(u1, u3);
    float2 s3 = make_float2(-(u1.y - u3.y), u1.x - u3.x);
    c[0][q2] = cadd(s0, s2);
    c[1][q2] = cadd(s1, s3);
    c[2][q2] = csub(s0, s2);
    c[3][q2] = csub(s1, s3);
  }
  #pragma unroll
  for (int q1 = 0; q1 < 4; ++q1)
    #pragma unroll
    for (int q2 = 0; q2 < 4; ++q2)
      Z[z0 + zoffk<Q1>(q1 * 4 + q2)] = c[q1][q2];
}

// single stage 6 (Q=1): all twiddles = 1; consecutive swizzled addresses
__device__ __forceinline__ void s6_fwd(float2* Z, int tid) {
  #pragma unroll 1
  for (int m = tid; m < FN / 4; m += NTHR) {
    const int zb = 4 * m + (m >> 2) + (m >> 4) + (m >> 8);
    float2 c0 = Z[zb], c1 = Z[zb + 1], c2 = Z[zb + 2], c3 = Z[zb + 3];
    float2 t0 = cadd(c0, c2), t1 = csub(c0, c2), t2 = cadd(c1, c3);
    float2 t3 = make_float2(c1.y - c3.y, -(c1.x - c3.x));
    Z[zb]     = cadd(t0, t2);
    Z[zb + 1] = cadd(t1, t3);
    Z[zb + 2] = csub(t0, t2);
    Z[zb + 3] = csub(t1, t3);
  }
}
__device__ __forceinline__ void s6_inv(float2* Z, int tid) {
  #pragma unroll 1
  for (int m = tid; m < FN / 4; m += NTHR) {
    const int zb = 4 * m + (m >> 2) + (m >> 4) + (m >> 8);
    float2 u0 = Z[zb], u1 = Z[zb + 1], u2 = Z[zb + 2], u3 = Z[zb + 3];
    float2 s0 = cadd(u0, u2), s1 = csub(u0, u2), s2 = cadd(u1, u3);
    float2 s3 = make_float2(-(u1.y - u3.y), u1.x - u3.x);
    Z[zb]     = cadd(s0, s2);
    Z[zb + 1] = cadd(s1, s3);
    Z[zb + 2] = csub(s0, s2);
    Z[zb + 3] = csub(s1, s3);
  }
}

__device__ void fft_fwd(float2* Z, const float2* __restrict__ tw, int tid) {
  ds_fwd<4096, 1>(Z, tw, tid);   __syncthreads();   // stages 0,1
  ds_fwd<256, 16>(Z, tw, tid);   __syncthreads();   // stages 2,3
  ds_fwd<16, 256>(Z, tw, tid);   __syncthreads();   // stages 4,5
  s6_fwd(Z, tid);                __syncthreads();   // stage 6
}
__device__ void fft_inv(float2* Z, const float2* __restrict__ tw, int tid) {
  s6_inv(Z, tid);                __syncthreads();
  ds_inv<16, 256>(Z, tw, tid);   __syncthreads();
  ds_inv<256, 16>(Z, tw, tid);   __syncthreads();
  ds_inv<4096, 1>(Z, tw, tid);   __syncthreads();
}

// twiddle tables: tw[e] = exp(-2 pi i e / 16384), tau[k] = exp(-i pi k / 16384)
__global__ void k_tw(float2* __restrict__ tw, float2* __restrict__ tau) {
  const int i = blockIdx.x * 256 + threadIdx.x;
  if (i < 12288) {
    const float ang = -6.283185307179586f * (float)i / 16384.0f;
    tw[i] = make_float2(cosf(ang), sinf(ang));
  }
  if (i <= 16384) {
    const float ang = -3.1415926535897932f * (float)i / 16384.0f;
    tau[i] = make_float2(cosf(ang), sinf(ang));
  }
}

// ---------------- kernel a construction (unchanged) ----------
__global__ void k_bands(const float* __restrict__ x,
                        const float* __restrict__ W1, const float* __restrict__ b1,
                        const float* __restrict__ W2, const float* __restrict__ b2,
                        const float* __restrict__ W3, const float* __restrict__ b3,
                        float* __restrict__ bands) {
  const int j = blockIdx.y;
  __shared__ float w2s[4096];
  __shared__ float w1s[64], b1s[64], b2s[64], w3s[64];
  for (int i = threadIdx.x; i < 4096; i += 256) w2s[i] = W2[j * 4096 + i];
  if (threadIdx.x < 64) {
    w1s[threadIdx.x] = W1[j * 64 + threadIdx.x];
    b1s[threadIdx.x] = b1[j * 64 + threadIdx.x];
    b2s[threadIdx.x] = b2[j * 64 + threadIdx.x];
    w3s[threadIdx.x] = W3[j * 64 + threadIdx.x];
  }
  __syncthreads();
  const int k = blockIdx.x * 256 + threadIdx.x;
  if (k >= 2049) return;
  const float xc = x[8 * k];
  float h1[64];
  #pragma unroll
  for (int o = 0; o < 64; ++o) h1[o] = tanhf(w1s[o] * xc + b1s[o]);
  float outv = b3[j];
  for (int o = 0; o < 64; ++o) {
    float a0 = 0.f, a1 = 0.f, a2 = 0.f, a3 = 0.f;
    #pragma unroll
    for (int c = 0; c < 64; c += 4) {
      a0 += w2s[o * 64 + c] * h1[c];
      a1 += w2s[o * 64 + c + 1] * h1[c + 1];
      a2 += w2s[o * 64 + c + 2] * h1[c + 2];
      a3 += w2s[o * 64 + c + 3] * h1[c + 3];
    }
    outv += w3s[o] * tanhf(b2s[o] + ((a0 + a1) + (a2 + a3)));
  }
  bands[j * 2049 + k] = outv;
}

// fused interp chain -> a in fp32, length 16385
__global__ void k_interp(const float* __restrict__ bands, float* __restrict__ af32) {
  __shared__ float s1[4097];
  __shared__ float s2[8193];
  const int tid = threadIdx.x;
  const float* bd0 = bands;
  const float* bd1 = bands + 2049;
  const float* bd2 = bands + 2 * 2049;
  for (int i = tid; i < 4097; i += 1024) {
    float v = (i & 1) ? 0.5f * (bd0[i >> 1] + bd0[(i >> 1) + 1]) : bd0[i >> 1];
    if (i >= 512 && i < 2561) v = bd1[i - 512];
    s1[i] = v;
  }
  __syncthreads();
  for (int i = tid; i < 8193; i += 1024) {
    float v = (i & 1) ? 0.5f * (s1[i >> 1] + s1[(i >> 1) + 1]) : s1[i >> 1];
    if (i >= 1024 && i < 3073) v = bd2[i - 1024];
    s2[i] = v;
  }
  __syncthreads();
  for (int i = tid; i < 16385; i += 1024) {
    float v = (i & 1) ? 0.5f * (s2[i >> 1] + s2[(i >> 1) + 1]) : s2[i >> 1];
    af32[i] = v;
  }
}

// A-hat: Ahat[k] = rfft_32768(a_pad)[k] / 16384, natural order, k in [0,16384].
__global__ __launch_bounds__(NTHR, 4) void k_ahat(const float* __restrict__ af32,
                                                  const float2* __restrict__ tw,
                                                  const float2* __restrict__ tau,
                                                  float2* __restrict__ Ahat) {
  __shared__ float2 Z[ZPAD];
  const int tid = threadIdx.x;
  for (int n = tid; n < FN; n += NTHR) {
    float2 v = make_float2(0.f, 0.f);
    if (n < 8192)       v = make_float2(af32[2 * n], af32[2 * n + 1]);
    else if (n == 8192) v = make_float2(af32[16384], 0.f);
    Z[ZIDX(n)] = v;
  }
  __syncthreads();
  fft_fwd(Z, tw, tid);
  const float sc = 1.0f / 16384.0f;
  for (int k = tid; k <= 16384; k += NTHR) {
    float2 A;
    if (k == 0) {
      float2 z0 = Z[ZIDX(0)];
      A = make_float2((z0.x + z0.y) * sc, 0.f);
    } else if (k == 16384) {
      float2 z0 = Z[ZIDX(0)];
      A = make_float2((z0.x - z0.y) * sc, 0.f);
    } else if (k == 8192) {
      float2 z8 = Z[ZIDX(rev4_14(8192))];
      A = make_float2(z8.x * sc, -z8.y * sc);
    } else {
      const int kc = 16384 - k;
      float2 Zk = Z[ZIDX(rev4_14(k))];
      float2 Zc = Z[ZIDX(rev4_14(kc))];
      float2 E = make_float2(0.5f * (Zk.x + Zc.x), 0.5f * (Zk.y - Zc.y));
      float2 D = make_float2(Zk.x - Zc.x, Zk.y + Zc.y);
      float2 O = make_float2(0.5f * D.y, -0.5f * D.x);
      float2 tk = tau[k];
      float2 tO = cmul(tk, O);
      A = make_float2((E.x + tO.x) * sc, (E.y + tO.y) * sc);
    }
    Ahat[k] = A;
  }
}

// Main conv kernel: one batch row per block (formulas verbatim from R10-R12).
__global__ __launch_bounds__(NTHR, 4) void k_conv(const float* __restrict__ u,
                                                  const float2* __restrict__ Ahat,
                                                  const float2* __restrict__ tw,
                                                  const float2* __restrict__ tau,
                                                  float* __restrict__ out) {
  __shared__ float2 Z[ZPAD];
  const int tid = threadIdx.x;
  const int b = blockIdx.x;
  const float* ub = u + (size_t)b * NN;

  for (int n = tid; n < FN; n += NTHR) {
    float2 v = make_float2(0.f, 0.f);
    if (n == 0)          v = make_float2(ub[8192], 0.f);
    else if (n >= 12288) {
      const int m = n - 12288;
      v = make_float2(ub[2 * m], ub[2 * m + 1]);
    }
    Z[ZIDX(n)] = v;
  }
  __syncthreads();

  fft_fwd(Z, tw, tid);

  // spectral multiply in the digit-reversed domain (pairs bijective, no sync)
  for (int i = tid; i < 8192; i += NTHR) {
    if (i == 0) {
      float2 z0 = Z[ZIDX(0)];
      float X0 = z0.x + z0.y;
      float XN = z0.x - z0.y;
      float Y0 = X0 * Ahat[0].x;
      float YN = XN * Ahat[16384].x;
      Z[ZIDX(0)] = make_float2(0.5f * (Y0 + YN), 0.5f * (Y0 - YN));
      const int r8 = rev4_14(8192);
      float2 z8 = Z[ZIDX(r8)];
      float2 X8 = make_float2(z8.x, -z8.y);
      float2 Y8 = cmul(X8, Ahat[8192]);
      Z[ZIDX(r8)] = make_float2(Y8.x, -Y8.y);
    } else {
      const int k = i, kc = 16384 - i;
      const int rk = ZIDX(rev4_14(k)), rkc = ZIDX(rev4_14(kc));
      float2 Zk = Z[rk], Zc = Z[rkc];
      float2 E = make_float2(0.5f * (Zk.x + Zc.x), 0.5f * (Zk.y - Zc.y));
      float2 D = make_float2(Zk.x - Zc.x, Zk.y + Zc.y);
      float2 O = make_float2(0.5f * D.y, -0.5f * D.x);
      float2 tk = tau[k];
      float2 tO = cmul(tk, O);
      float2 Xk = make_float2(E.x + tO.x, E.y + tO.y);
      float2 Xc = make_float2(E.x - tO.x, -(E.y - tO.y));
      float2 Yk = cmul(Xk, Ahat[k]);
      float2 Y2 = cmul(Xc, Ahat[kc]);
      float2 Ep = make_float2(0.5f * (Yk.x + Y2.x), 0.5f * (Yk.y - Y2.y));
      float2 D2 = make_float2(0.5f * (Yk.x - Y2.x), 0.5f * (Yk.y + Y2.y));
      float2 tb = make_float2(tk.x, -tk.y);
      float2 Op = cmul(tb, D2);
      Z[rk]  = make_float2(Ep.x - Op.y, Ep.y + Op.x);
      Z[rkc] = make_float2(Ep.x + Op.y, -Ep.y + Op.x);
    }
  }
  __syncthreads();

  fft_inv(Z, tw, tid);

  float* ob = out + (size_t)b * NN;
  for (int n = tid; n <= 4096; n += NTHR) {
    float2 w = Z[ZIDX(n)];
    if (n < 4096) {
      ob[2 * n]     = w.x;
      ob[2 * n + 1] = w.y;
    } else {
      ob[8192] = w.x;
    }
  }
}

extern "C" void kernel_launch(void* const* d_in, const int* in_sizes, int n_in,
                              void* d_out, int out_size, void* d_ws, size_t ws_size,
                              hipStream_t stream) {
  (void)in_sizes; (void)n_in; (void)out_size; (void)ws_size;
  const float* u  = (const float*)d_in[0];
  const float* x  = (const float*)d_in[1];
  const float* W1 = (const float*)d_in[2];
  const float* b1 = (const float*)d_in[3];
  const float* W2 = (const float*)d_in[4];
  const float* b2 = (const float*)d_in[5];
  const float* W3 = (const float*)d_in[6];
  const float* b3 = (const float*)d_in[7];
  float* out = (float*)d_out;
  char*  ws  = (char*)d_ws;

  float*  bands = (float*)(ws + OFF_BANDS);
  float*  af32  = (float*)(ws + OFF_AF32);
  float2* Ahat  = (float2*)(ws + OFF_AHAT);
  float2* tw    = (float2*)(ws + OFF_TW);
  float2* tau   = (float2*)(ws + OFF_TAU);

  k_tw<<<65, 256, 0, stream>>>(tw, tau);
  k_bands<<<dim3(9, 3), 256, 0, stream>>>(x, W1, b1, W2, b2, W3, b3, bands);
  k_interp<<<1, 1024, 0, stream>>>(bands, af32);
  k_ahat<<<1, NTHR, 0, stream>>>(af32, tw, tau, Ahat);
  k_conv<<<1024, NTHR, 0, stream>>>(u, Ahat, tw, tau, out);
}

// Round 14
// 215.262 us; speedup vs baseline: 1.4268x; 1.4268x over previous
//
#include <hip/hip_runtime.h>

#define NN  8193       // output cols per row; u length
#define FN  16384      // complex FFT length (real conv length 32768)
#define NTHR 1024      // threads per FFT block

// LDS swizzle-pad (R12-verified): bank-pair stride classes (mod 16):
// 1->1, 4->4, 64->5, 256->4, 1024->1. Injective. Max ZIDX(16383) = 17676.
#define ZIDX(i) ((i) + ((i) >> 4) + ((i) >> 6) + ((i) >> 10))
#define ZPAD 17680

// workspace byte offsets (256-aligned)
#define OFF_BANDS 0u        // 3*2049*4
#define OFF_AF32  24832u    // 16385*4
#define OFF_AHAT  90624u    // 16385*8
#define OFF_TW    221952u   // 4096*8 = 32768 (w_N^e, e in [0,4096) — L1-resident)
#define OFF_TAU   320256u   // 16385*8 (exp(-i pi k/N))

__device__ __forceinline__ float2 cmul(float2 a, float2 b) {
  return make_float2(a.x * b.x - a.y * b.y, a.x * b.y + a.y * b.x);
}
__device__ __forceinline__ float2 cadd(float2 a, float2 b) { return make_float2(a.x + b.x, a.y + b.y); }
__device__ __forceinline__ float2 csub(float2 a, float2 b) { return make_float2(a.x - b.x, a.y - b.y); }

// base-4 digit reversal of 7 digits (14 bits)
__device__ __forceinline__ int rev4_14(int k) {
  int r = 0;
  #pragma unroll
  for (int i = 0; i < 7; ++i) { r = (r << 2) | (k & 3); k >>= 2; }
  return r;
}

// Single radix-4 stage with affine swizzled offsets.
// ZIDX(base + k*Q) = ZIDX(base) + ZO*k, valid per-stage by carry analysis:
// kQ is a multiple of each shift boundary it contributes to, and j<Q plus
// structural zeros in base block all carries.
//   Q=4096: 4096+256+64+4 = 4420 | Q=1024: 1024+64+16+1 = 1105
//   Q=256:  256+16+4      = 276  | Q=64:   64+4+1       = 69
//   Q=16:   16+1          = 17   | Q=4:    4            = 4
// Twiddle: w1 = tw[j*M] (j*M < FN/4 = 4096), w2 = w1^2, w3 = w1*w2.
// Butterfly formulas verbatim from the R10-verified stages.
template<int Q, int M, bool INV>
__device__ __forceinline__ void stage4(float2* Z, const float2* __restrict__ tw,
                                       int tid) {
  constexpr int ZO = (Q == 4096) ? 4420 : (Q == 1024) ? 1105 : (Q == 256) ? 276
                   : (Q == 64)   ? 69   : (Q == 16)   ? 17   : 4;
  #pragma unroll 1
  for (int r = 0; r < FN / 4 / NTHR; ++r) {
    const int idx = tid + r * NTHR;
    const int j  = idx & (Q - 1);
    const int b1 = idx / Q;                 // compile-time shift
    const int z0 = ZIDX(b1 * 4 * Q + j);
    float2 w1 = tw[j * M];
    if (INV) w1.y = -w1.y;
    const float2 w2 = cmul(w1, w1);
    const float2 w3 = cmul(w1, w2);
    if (!INV) {
      float2 c0 = Z[z0], c1 = Z[z0 + ZO], c2 = Z[z0 + 2 * ZO], c3 = Z[z0 + 3 * ZO];
      float2 t0 = cadd(c0, c2), t1 = csub(c0, c2), t2 = cadd(c1, c3);
      float2 t3 = make_float2(c1.y - c3.y, -(c1.x - c3.x));   // -i*(c1-c3)
      Z[z0]          = cadd(t0, t2);
      Z[z0 + ZO]     = cmul(w1, cadd(t1, t3));
      Z[z0 + 2 * ZO] = cmul(w2, csub(t0, t2));
      Z[z0 + 3 * ZO] = cmul(w3, csub(t1, t3));
    } else {
      float2 u0 = Z[z0];
      float2 u1 = cmul(w1, Z[z0 + ZO]);
      float2 u2 = cmul(w2, Z[z0 + 2 * ZO]);
      float2 u3 = cmul(w3, Z[z0 + 3 * ZO]);
      float2 s0 = cadd(u0, u2), s1 = csub(u0, u2), s2 = cadd(u1, u3);
      float2 s3 = make_float2(-(u1.y - u3.y), u1.x - u3.x);   // +i*(u1-u3)
      Z[z0]          = cadd(s0, s2);
      Z[z0 + ZO]     = cadd(s1, s3);
      Z[z0 + 2 * ZO] = csub(s0, s2);
      Z[z0 + 3 * ZO] = csub(s1, s3);
    }
  }
}

// stage 6 (Q=1): all twiddles = 1; swizzled base 4m + m>>2 + m>>4 + m>>8,
// +k offsets exact (no carry: low bits (m&3)<<2 + k <= 15).
__device__ __forceinline__ void s6_fwd(float2* Z, int tid) {
  #pragma unroll 1
  for (int m = tid; m < FN / 4; m += NTHR) {
    const int zb = 4 * m + (m >> 2) + (m >> 4) + (m >> 8);
    float2 c0 = Z[zb], c1 = Z[zb + 1], c2 = Z[zb + 2], c3 = Z[zb + 3];
    float2 t0 = cadd(c0, c2), t1 = csub(c0, c2), t2 = cadd(c1, c3);
    float2 t3 = make_float2(c1.y - c3.y, -(c1.x - c3.x));
    Z[zb]     = cadd(t0, t2);
    Z[zb + 1] = cadd(t1, t3);
    Z[zb + 2] = csub(t0, t2);
    Z[zb + 3] = csub(t1, t3);
  }
}
__device__ __forceinline__ void s6_inv(float2* Z, int tid) {
  #pragma unroll 1
  for (int m = tid; m < FN / 4; m += NTHR) {
    const int zb = 4 * m + (m >> 2) + (m >> 4) + (m >> 8);
    float2 u0 = Z[zb], u1 = Z[zb + 1], u2 = Z[zb + 2], u3 = Z[zb + 3];
    float2 s0 = cadd(u0, u2), s1 = csub(u0, u2), s2 = cadd(u1, u3);
    float2 s3 = make_float2(-(u1.y - u3.y), u1.x - u3.x);
    Z[zb]     = cadd(s0, s2);
    Z[zb + 1] = cadd(s1, s3);
    Z[zb + 2] = csub(s0, s2);
    Z[zb + 3] = csub(s1, s3);
  }
}

__device__ void fft_fwd(float2* Z, const float2* __restrict__ tw, int tid) {
  stage4<4096, 1, false>(Z, tw, tid);   __syncthreads();
  stage4<1024, 4, false>(Z, tw, tid);   __syncthreads();
  stage4<256, 16, false>(Z, tw, tid);   __syncthreads();
  stage4<64, 64, false>(Z, tw, tid);    __syncthreads();
  stage4<16, 256, false>(Z, tw, tid);   __syncthreads();
  stage4<4, 1024, false>(Z, tw, tid);   __syncthreads();
  s6_fwd(Z, tid);                       __syncthreads();
}
__device__ void fft_inv(float2* Z, const float2* __restrict__ tw, int tid) {
  s6_inv(Z, tid);                       __syncthreads();
  stage4<4, 1024, true>(Z, tw, tid);    __syncthreads();
  stage4<16, 256, true>(Z, tw, tid);    __syncthreads();
  stage4<64, 64, true>(Z, tw, tid);     __syncthreads();
  stage4<256, 16, true>(Z, tw, tid);    __syncthreads();
  stage4<1024, 4, true>(Z, tw, tid);    __syncthreads();
  stage4<4096, 1, true>(Z, tw, tid);    __syncthreads();
}

// twiddle tables: tw[e] = exp(-2 pi i e / 16384) for e<4096 (32KB, L1-resident),
// tau[k] = exp(-i pi k / 16384)
__global__ void k_tw(float2* __restrict__ tw, float2* __restrict__ tau) {
  const int i = blockIdx.x * 256 + threadIdx.x;
  if (i < 4096) {
    const float ang = -6.283185307179586f * (float)i / 16384.0f;
    tw[i] = make_float2(cosf(ang), sinf(ang));
  }
  if (i <= 16384) {
    const float ang = -3.1415926535897932f * (float)i / 16384.0f;
    tau[i] = make_float2(cosf(ang), sinf(ang));
  }
}

// ---------------- kernel a construction (unchanged) ----------
__global__ void k_bands(const float* __restrict__ x,
                        const float* __restrict__ W1, const float* __restrict__ b1,
                        const float* __restrict__ W2, const float* __restrict__ b2,
                        const float* __restrict__ W3, const float* __restrict__ b3,
                        float* __restrict__ bands) {
  const int j = blockIdx.y;
  __shared__ float w2s[4096];
  __shared__ float w1s[64], b1s[64], b2s[64], w3s[64];
  for (int i = threadIdx.x; i < 4096; i += 256) w2s[i] = W2[j * 4096 + i];
  if (threadIdx.x < 64) {
    w1s[threadIdx.x] = W1[j * 64 + threadIdx.x];
    b1s[threadIdx.x] = b1[j * 64 + threadIdx.x];
    b2s[threadIdx.x] = b2[j * 64 + threadIdx.x];
    w3s[threadIdx.x] = W3[j * 64 + threadIdx.x];
  }
  __syncthreads();
  const int k = blockIdx.x * 256 + threadIdx.x;
  if (k >= 2049) return;
  const float xc = x[8 * k];
  float h1[64];
  #pragma unroll
  for (int o = 0; o < 64; ++o) h1[o] = tanhf(w1s[o] * xc + b1s[o]);
  float outv = b3[j];
  for (int o = 0; o < 64; ++o) {
    float a0 = 0.f, a1 = 0.f, a2 = 0.f, a3 = 0.f;
    #pragma unroll
    for (int c = 0; c < 64; c += 4) {
      a0 += w2s[o * 64 + c] * h1[c];
      a1 += w2s[o * 64 + c + 1] * h1[c + 1];
      a2 += w2s[o * 64 + c + 2] * h1[c + 2];
      a3 += w2s[o * 64 + c + 3] * h1[c + 3];
    }
    outv += w3s[o] * tanhf(b2s[o] + ((a0 + a1) + (a2 + a3)));
  }
  bands[j * 2049 + k] = outv;
}

// fused interp chain -> a in fp32, length 16385
__global__ void k_interp(const float* __restrict__ bands, float* __restrict__ af32) {
  __shared__ float s1[4097];
  __shared__ float s2[8193];
  const int tid = threadIdx.x;
  const float* bd0 = bands;
  const float* bd1 = bands + 2049;
  const float* bd2 = bands + 2 * 2049;
  for (int i = tid; i < 4097; i += 1024) {
    float v = (i & 1) ? 0.5f * (bd0[i >> 1] + bd0[(i >> 1) + 1]) : bd0[i >> 1];
    if (i >= 512 && i < 2561) v = bd1[i - 512];
    s1[i] = v;
  }
  __syncthreads();
  for (int i = tid; i < 8193; i += 1024) {
    float v = (i & 1) ? 0.5f * (s1[i >> 1] + s1[(i >> 1) + 1]) : s1[i >> 1];
    if (i >= 1024 && i < 3073) v = bd2[i - 1024];
    s2[i] = v;
  }
  __syncthreads();
  for (int i = tid; i < 16385; i += 1024) {
    float v = (i & 1) ? 0.5f * (s2[i >> 1] + s2[(i >> 1) + 1]) : s2[i >> 1];
    af32[i] = v;
  }
}

// A-hat: Ahat[k] = rfft_32768(a_pad)[k] / 16384, natural order, k in [0,16384].
__global__ __launch_bounds__(NTHR, 4) void k_ahat(const float* __restrict__ af32,
                                                  const float2* __restrict__ tw,
                                                  const float2* __restrict__ tau,
                                                  float2* __restrict__ Ahat) {
  __shared__ float2 Z[ZPAD];
  const int tid = threadIdx.x;
  for (int n = tid; n < FN; n += NTHR) {
    float2 v = make_float2(0.f, 0.f);
    if (n < 8192)       v = make_float2(af32[2 * n], af32[2 * n + 1]);
    else if (n == 8192) v = make_float2(af32[16384], 0.f);
    Z[ZIDX(n)] = v;
  }
  __syncthreads();
  fft_fwd(Z, tw, tid);
  const float sc = 1.0f / 16384.0f;
  for (int k = tid; k <= 16384; k += NTHR) {
    float2 A;
    if (k == 0) {
      float2 z0 = Z[ZIDX(0)];
      A = make_float2((z0.x + z0.y) * sc, 0.f);
    } else if (k == 16384) {
      float2 z0 = Z[ZIDX(0)];
      A = make_float2((z0.x - z0.y) * sc, 0.f);
    } else if (k == 8192) {
      float2 z8 = Z[ZIDX(rev4_14(8192))];
      A = make_float2(z8.x * sc, -z8.y * sc);
    } else {
      const int kc = 16384 - k;
      float2 Zk = Z[ZIDX(rev4_14(k))];
      float2 Zc = Z[ZIDX(rev4_14(kc))];
      float2 E = make_float2(0.5f * (Zk.x + Zc.x), 0.5f * (Zk.y - Zc.y));
      float2 D = make_float2(Zk.x - Zc.x, Zk.y + Zc.y);
      float2 O = make_float2(0.5f * D.y, -0.5f * D.x);
      float2 tk = tau[k];
      float2 tO = cmul(tk, O);
      A = make_float2((E.x + tO.x) * sc, (E.y + tO.y) * sc);
    }
    Ahat[k] = A;
  }
}

// Main conv kernel: one batch row per block (formulas verbatim from R10-R13).
__global__ __launch_bounds__(NTHR, 4) void k_conv(const float* __restrict__ u,
                                                  const float2* __restrict__ Ahat,
                                                  const float2* __restrict__ tw,
                                                  const float2* __restrict__ tau,
                                                  float* __restrict__ out) {
  __shared__ float2 Z[ZPAD];
  const int tid = threadIdx.x;
  const int b = blockIdx.x;
  const float* ub = u + (size_t)b * NN;

  for (int n = tid; n < FN; n += NTHR) {
    float2 v = make_float2(0.f, 0.f);
    if (n == 0)          v = make_float2(ub[8192], 0.f);
    else if (n >= 12288) {
      const int m = n - 12288;
      v = make_float2(ub[2 * m], ub[2 * m + 1]);
    }
    Z[ZIDX(n)] = v;
  }
  __syncthreads();

  fft_fwd(Z, tw, tid);

  // spectral multiply in the digit-reversed domain (pairs bijective, no sync)
  for (int i = tid; i < 8192; i += NTHR) {
    if (i == 0) {
      float2 z0 = Z[ZIDX(0)];
      float X0 = z0.x + z0.y;
      float XN = z0.x - z0.y;
      float Y0 = X0 * Ahat[0].x;
      float YN = XN * Ahat[16384].x;
      Z[ZIDX(0)] = make_float2(0.5f * (Y0 + YN), 0.5f * (Y0 - YN));
      const int r8 = rev4_14(8192);
      float2 z8 = Z[ZIDX(r8)];
      float2 X8 = make_float2(z8.x, -z8.y);
      float2 Y8 = cmul(X8, Ahat[8192]);
      Z[ZIDX(r8)] = make_float2(Y8.x, -Y8.y);
    } else {
      const int k = i, kc = 16384 - i;
      const int rk = ZIDX(rev4_14(k)), rkc = ZIDX(rev4_14(kc));
      float2 Zk = Z[rk], Zc = Z[rkc];
      float2 E = make_float2(0.5f * (Zk.x + Zc.x), 0.5f * (Zk.y - Zc.y));
      float2 D = make_float2(Zk.x - Zc.x, Zk.y + Zc.y);
      float2 O = make_float2(0.5f * D.y, -0.5f * D.x);
      float2 tk = tau[k];
      float2 tO = cmul(tk, O);
      float2 Xk = make_float2(E.x + tO.x, E.y + tO.y);
      float2 Xc = make_float2(E.x - tO.x, -(E.y - tO.y));
      float2 Yk = cmul(Xk, Ahat[k]);
      float2 Y2 = cmul(Xc, Ahat[kc]);
      float2 Ep = make_float2(0.5f * (Yk.x + Y2.x), 0.5f * (Yk.y - Y2.y));
      float2 D2 = make_float2(0.5f * (Yk.x - Y2.x), 0.5f * (Yk.y + Y2.y));
      float2 tb = make_float2(tk.x, -tk.y);
      float2 Op = cmul(tb, D2);
      Z[rk]  = make_float2(Ep.x - Op.y, Ep.y + Op.x);
      Z[rkc] = make_float2(Ep.x + Op.y, -Ep.y + Op.x);
    }
  }
  __syncthreads();

  fft_inv(Z, tw, tid);

  float* ob = out + (size_t)b * NN;
  for (int n = tid; n <= 4096; n += NTHR) {
    float2 w = Z[ZIDX(n)];
    if (n < 4096) {
      ob[2 * n]     = w.x;
      ob[2 * n + 1] = w.y;
    } else {
      ob[8192] = w.x;
    }
  }
}

extern "C" void kernel_launch(void* const* d_in, const int* in_sizes, int n_in,
                              void* d_out, int out_size, void* d_ws, size_t ws_size,
                              hipStream_t stream) {
  (void)in_sizes; (void)n_in; (void)out_size; (void)ws_size;
  const float* u  = (const float*)d_in[0];
  const float* x  = (const float*)d_in[1];
  const float* W1 = (const float*)d_in[2];
  const float* b1 = (const float*)d_in[3];
  const float* W2 = (const float*)d_in[4];
  const float* b2 = (const float*)d_in[5];
  const float* W3 = (const float*)d_in[6];
  const float* b3 = (const float*)d_in[7];
  float* out = (float*)d_out;
  char*  ws  = (char*)d_ws;

  float*  bands = (float*)(ws + OFF_BANDS);
  float*  af32  = (float*)(ws + OFF_AF32);
  float2* Ahat  = (float2*)(ws + OFF_AHAT);
  float2* tw    = (float2*)(ws + OFF_TW);
  float2* tau   = (float2*)(ws + OFF_TAU);

  k_tw<<<65, 256, 0, stream>>>(tw, tau);
  k_bands<<<dim3(9, 3), 256, 0, stream>>>(x, W1, b1, W2, b2, W3, b3, bands);
  k_interp<<<1, 1024, 0, stream>>>(bands, af32);
  k_ahat<<<1, NTHR, 0, stream>>>(af32, tw, tau, Ahat);
  k_conv<<<1024, NTHR, 0, stream>>>(u, Ahat, tw, tau, out);
}